// Round 2
// baseline (145.428 us; speedup 1.0000x reference)
//
#include <hip/hip_runtime.h>
#include <hip/hip_bf16.h>
#include <math.h>

#define NB    4
#define NC    128
#define NH    56
#define NW    56
#define HP    62
#define NPIX  3136      // 56*56
#define NPPIX 3844      // 62*62
#define CHW   401408    // 128*3136
#define CPHW  492032    // 128*3844
#define KPAD_N 1968128  // 4*128*3844
#define SKSTRIDE 68     // padded LDS row stride for K/V images

// ---------------- prep: bias-fill HALO of padded K/V, transpose weights ----
__global__ __launch_bounds__(256) void prep_kernel(
    const float* __restrict__ qw, const float* __restrict__ kw,
    const float* __restrict__ vw, const float* __restrict__ kb,
    const float* __restrict__ vb, const float* __restrict__ rel_h,
    const float* __restrict__ rel_w,
    float* __restrict__ kpad, float* __restrict__ vpad,
    float* __restrict__ wTq, float* __restrict__ wTk, float* __restrict__ wTv,
    float* __restrict__ rb)
{
    int idx = blockIdx.x * 256 + threadIdx.x;
    if (idx < KPAD_N) {
        int p = idx % NPPIX;
        int yy = p / 62, xx = p - yy * 62;
        if (yy < 3 || yy > 58 || xx < 3 || xx > 58) {  // halo only; conv fills interior
            int ch = (idx / NPPIX) & 127;
            kpad[idx] = kb[ch];
            vpad[idx] = vb[ch];
        }
    }
    if (idx < 3 * 16384) {
        int m = idx >> 14;
        int r = idx & 16383;
        int o = r >> 7, c = r & 127;
        const float* src = (m == 0) ? qw : (m == 1) ? kw : vw;
        float* dst = (m == 0) ? wTq : (m == 1) ? wTk : wTv;
        dst[c * 128 + o] = src[o * 128 + c];
    }
    if (idx < 14) {
        const float* src = (idx < 7) ? rel_h : rel_w;
        int off = (idx < 7) ? idx : idx - 7;
        float s = 0.f;
        for (int c = 0; c < 64; ++c) s += src[c * 7 + off];
        rb[idx] = s;
    }
}

// ---------------- conv: fused 1x1 convs Q,K,V (inner region) ---------------
__global__ __launch_bounds__(256) void conv_kernel(
    const float* __restrict__ x,
    const float* __restrict__ wTq, const float* __restrict__ wTk,
    const float* __restrict__ wTv,
    const float* __restrict__ qb, const float* __restrict__ kb,
    const float* __restrict__ vb,
    float* __restrict__ q, float* __restrict__ kpad, float* __restrict__ vpad)
{
    __shared__ float sx[128 * 56];
    int bid = blockIdx.x;
    int osplit = bid & 1;
    int y = (bid >> 1) % 56;
    int b = bid / 112;
    const float* xb = x + b * CHW + y * 56;
    for (int i = threadIdx.x; i < 128 * 56; i += 256) {
        int c = i / 56;
        sx[i] = xb[c * NPIX + (i - c * 56)];
    }
    __syncthreads();
    if (threadIdx.x >= 224) return;
    int xg = threadIdx.x % 14;
    int og = threadIdx.x / 14;
    int o0 = osplit * 64 + og * 4;

    float aq[4][4] = {}, ak[4][4] = {}, av[4][4] = {};
    #pragma unroll 4
    for (int c = 0; c < 128; ++c) {
        float4 xv4 = *(const float4*)&sx[c * 56 + xg * 4];
        float4 wq4 = *(const float4*)&wTq[c * 128 + o0];
        float4 wk4 = *(const float4*)&wTk[c * 128 + o0];
        float4 wv4 = *(const float4*)&wTv[c * 128 + o0];
        float xr[4] = {xv4.x, xv4.y, xv4.z, xv4.w};
        float qr[4] = {wq4.x, wq4.y, wq4.z, wq4.w};
        float kr[4] = {wk4.x, wk4.y, wk4.z, wk4.w};
        float vr[4] = {wv4.x, wv4.y, wv4.z, wv4.w};
        #pragma unroll
        for (int oi = 0; oi < 4; ++oi)
            #pragma unroll
            for (int xi = 0; xi < 4; ++xi) {
                aq[oi][xi] += qr[oi] * xr[xi];
                ak[oi][xi] += kr[oi] * xr[xi];
                av[oi][xi] += vr[oi] * xr[xi];
            }
    }
    #pragma unroll
    for (int oi = 0; oi < 4; ++oi) {
        int o = o0 + oi;
        float bq = qb[o], bk = kb[o], bv = vb[o];
        float* qdst = q + b * CHW + o * NPIX + y * 56 + xg * 4;
        float4 qv4 = {aq[oi][0] + bq, aq[oi][1] + bq, aq[oi][2] + bq, aq[oi][3] + bq};
        *(float4*)qdst = qv4;
        float* kdst = kpad + b * CPHW + o * NPPIX + (y + 3) * 62 + xg * 4 + 3;
        float* vdst = vpad + b * CPHW + o * NPPIX + (y + 3) * 62 + xg * 4 + 3;
        #pragma unroll
        for (int xi = 0; xi < 4; ++xi) {
            kdst[xi] = ak[oi][xi] + bk;
            vdst[xi] = av[oi][xi] + bv;
        }
    }
}

// ---------------- attn: per-(b,c,row-quarter) local attention --------------
// Block = one (b,c) x one quarter of rows (14 image rows = 49 groups).
// LDS: sQ 784 floats + sK/sV 20 padded rows x 68 stride = 14.0 KB/block.
__global__ __launch_bounds__(256) void attn_kernel(
    const float* __restrict__ q, const float* __restrict__ kpad,
    const float* __restrict__ vpad, const float* __restrict__ rb,
    float* __restrict__ out)
{
    __shared__ float sQ[784];
    __shared__ float sK[20 * SKSTRIDE];
    __shared__ float sV[20 * SKSTRIDE];
    int bid = blockIdx.x;
    int qpart = bid & 3;
    int bc = bid >> 2;
    const float* qc = q + bc * NPIX + 784 * qpart;
    const float* kc = kpad + (size_t)bc * NPPIX + (14 * qpart) * 62;
    const float* vc = vpad + (size_t)bc * NPPIX + (14 * qpart) * 62;
    float* oc = out + bc * NPIX;

    for (int i = threadIdx.x; i < 784 / 4; i += 256)
        ((float4*)sQ)[i] = ((const float4*)qc)[i];
    for (int i = threadIdx.x; i < 20 * 62; i += 256) {
        int yy = i / 62;
        int xx = i - yy * 62;
        sK[yy * SKSTRIDE + xx] = kc[i];
        sV[yy * SKSTRIDE + xx] = vc[i];
    }
    __syncthreads();

    int lane = threadIdx.x & 63;
    int wave = threadIdx.x >> 6;
    int k2 = (lane < 49) ? lane : 48;
    int di = k2 / 7, dj = k2 - (k2 / 7) * 7;
    float rbias = rb[di] + rb[7 + dj];
    int koff = di * SKSTRIDE + dj;
    int t16 = lane & 15, p = lane >> 4;
    // PV per-lane precompute
    int kk0 = p * 13;
    int dj0 = kk0 % 7;
    int rel0 = (kk0 / 7) * SKSTRIDE + dj0;
    int nk = (p == 3) ? 10 : 13;

    for (int gl = wave; gl < 49; gl += 4) {
        int ul0 = gl * 16;                    // local pixel base (within quarter)
        int y0 = ul0 / 56;                    // local image row 0..13
        int x0 = ul0 - y0 * 56;

        // --- qk: 49 lanes, 16 MACs each -------------------------------
        float acc = 0.f, qs = 0.f;
        int base = y0 * SKSTRIDE + x0;
        int xcur = x0;
        #pragma unroll
        for (int t = 0; t < 16; ++t) {
            float qv = sQ[ul0 + t];
            qs += qv;
            acc += qv * sK[base + koff];
            int wrap = (xcur == 55);
            base += wrap ? (SKSTRIDE - 55) : 1;
            xcur = wrap ? 0 : (xcur + 1);
        }
        float val = (lane < 49) ? (acc + qs * rbias) : -1e30f;

        // --- softmax over 49 (wave-wide shfl reduce) ------------------
        float m = val;
        #pragma unroll
        for (int off = 32; off >= 1; off >>= 1)
            m = fmaxf(m, __shfl_xor(m, off));
        float e = (lane < 49) ? __expf(val - m) : 0.f;
        float s = e;
        #pragma unroll
        for (int off = 32; off >= 1; off >>= 1)
            s += __shfl_xor(s, off);
        float wv = __fdividef(e, s);

        // --- PV: lanes = 16 t x 4 k-chunks ----------------------------
        int ul = ul0 + t16;
        int yt = ul / 56;
        int xt = ul - yt * 56;
        int voff = yt * SKSTRIDE + xt + rel0;
        int djc = dj0;
        float oacc = 0.f;
        #pragma unroll
        for (int k2i = 0; k2i < 13; ++k2i) {
            float wk = __shfl(wv, kk0 + k2i);
            if (k2i < nk) oacc += wk * sV[voff];
            int wrap = (djc == 6);
            voff += wrap ? (SKSTRIDE - 6) : 1;
            djc = wrap ? 0 : (djc + 1);
        }
        oacc += __shfl_xor(oacc, 16);
        oacc += __shfl_xor(oacc, 32);
        if (lane < 16) oc[(qpart * 49 + gl) * 16 + lane] = oacc;
    }
}

extern "C" void kernel_launch(void* const* d_in, const int* in_sizes, int n_in,
                              void* d_out, int out_size, void* d_ws, size_t ws_size,
                              hipStream_t stream) {
    const float* x     = (const float*)d_in[0];
    const float* qw    = (const float*)d_in[1];
    const float* qb    = (const float*)d_in[2];
    const float* kw    = (const float*)d_in[3];
    const float* kb    = (const float*)d_in[4];
    const float* vw    = (const float*)d_in[5];
    const float* vb    = (const float*)d_in[6];
    const float* rel_h = (const float*)d_in[7];
    const float* rel_w = (const float*)d_in[8];
    float* out = (float*)d_out;

    float* ws   = (float*)d_ws;
    float* kpad = ws;                    // 1968128
    float* vpad = kpad + KPAD_N;         // 1968128
    float* qbuf = vpad + KPAD_N;         // 1605632
    float* wTq  = qbuf + 1605632;        // 16384
    float* wTk  = wTq + 16384;
    float* wTv  = wTk + 16384;
    float* rb   = wTv + 16384;           // 16

    prep_kernel<<<KPAD_N / 256, 256, 0, stream>>>(qw, kw, vw, kb, vb, rel_h, rel_w,
                                                  kpad, vpad, wTq, wTk, wTv, rb);
    conv_kernel<<<448, 256, 0, stream>>>(x, wTq, wTk, wTv, qb, kb, vb,
                                         qbuf, kpad, vpad);
    attn_kernel<<<2048, 256, 0, stream>>>(qbuf, kpad, vpad, rb, out);
}

// Round 4
// 105.920 us; speedup vs baseline: 1.3730x; 1.3730x over previous
//
#include <hip/hip_runtime.h>
#include <hip/hip_bf16.h>
#include <math.h>

#define NB    4
#define NC    128
#define NPIX  3136      // 56*56
#define NPPIX 3844      // 62*62
#define CHW   401408    // 128*3136
#define CPHW  492032    // 128*3844
#define KPAD_N 1968128  // 4*128*3844
#define SKS   68        // padded LDS row stride for K/V images

// ---------- DPP wave64 reduce helpers (VALU pipe, no DS) -------------------
template <int CTRL, int RM>
__device__ __forceinline__ float dpp_mov(float x, float old) {
    return __int_as_float(__builtin_amdgcn_update_dpp(
        __float_as_int(old), __float_as_int(x), CTRL, RM, 0xf, false));
}
__device__ __forceinline__ float wave_max(float x) {
    x = fmaxf(x, dpp_mov<0x111, 0xf>(x, x));   // row_shr:1
    x = fmaxf(x, dpp_mov<0x112, 0xf>(x, x));   // row_shr:2
    x = fmaxf(x, dpp_mov<0x114, 0xf>(x, x));   // row_shr:4
    x = fmaxf(x, dpp_mov<0x118, 0xf>(x, x));   // row_shr:8
    x = fmaxf(x, dpp_mov<0x142, 0xa>(x, x));   // row_bcast:15 -> rows 1,3
    x = fmaxf(x, dpp_mov<0x143, 0xc>(x, x));   // row_bcast:31 -> rows 2,3
    return __int_as_float(__builtin_amdgcn_readlane(__float_as_int(x), 63));
}
__device__ __forceinline__ float wave_sum(float x) {
    x = x + dpp_mov<0x111, 0xf>(x, 0.f);
    x = x + dpp_mov<0x112, 0xf>(x, 0.f);
    x = x + dpp_mov<0x114, 0xf>(x, 0.f);
    x = x + dpp_mov<0x118, 0xf>(x, 0.f);
    x = x + dpp_mov<0x142, 0xa>(x, 0.f);
    x = x + dpp_mov<0x143, 0xc>(x, 0.f);
    return __int_as_float(__builtin_amdgcn_readlane(__float_as_int(x), 63));
}

// ---------------- prep: halo bias-fill + weight transpose + rel sums -------
__global__ __launch_bounds__(256) void prep_kernel(
    const float* __restrict__ qw, const float* __restrict__ kw,
    const float* __restrict__ vw,
    const float* __restrict__ kb, const float* __restrict__ vb,
    const float* __restrict__ rel_h, const float* __restrict__ rel_w,
    float* __restrict__ kpad, float* __restrict__ vpad,
    float* __restrict__ wTq, float* __restrict__ wTk, float* __restrict__ wTv,
    float* __restrict__ rb)
{
    int idx = blockIdx.x * 256 + threadIdx.x;
    {   // halo fill: 708 positions per image, 512 images
        int img = idx / 708;
        int hl = idx - img * 708;
        int p;
        if (hl < 186) p = hl;                           // rows 0..2
        else if (hl < 372) p = 3658 + (hl - 186);       // rows 59..61
        else {
            int j = hl - 372;
            int r = j / 6, cc = j - r * 6;
            p = (r + 3) * 62 + (cc < 3 ? cc : cc + 56); // cols 0-2, 59-61
        }
        int ch = img & 127;
        size_t o = (size_t)img * NPPIX + p;
        kpad[o] = kb[ch];
        vpad[o] = vb[ch];
    }
    if (idx < 3 * 16384) {
        int m = idx >> 14;
        int r = idx & 16383;
        int o = r >> 7, c = r & 127;
        const float* src = (m == 0) ? qw : (m == 1) ? kw : vw;
        float* dst = (m == 0) ? wTq : (m == 1) ? wTk : wTv;
        dst[c * 128 + o] = src[o * 128 + c];
    }
    if (idx < 14) {
        const float* src = (idx < 7) ? rel_h : rel_w;
        int off = (idx < 7) ? idx : idx - 7;
        float s = 0.f;
        for (int c = 0; c < 64; ++c) s += src[c * 7 + off];
        rb[idx] = s;
    }
}

// ---------------- conv: fused 1x1 convs Q,K,V (fp32) -----------------------
// block = (b, 32-pixel tile, osplit of 64 outs). 256 thr = 16 xg x 16 og.
// per thread: 4 outs x 2 pixels x 3 mats. LDS 16KB fp32. grid = 4*98*2 = 784.
__global__ __launch_bounds__(256) void conv_kernel(
    const float* __restrict__ x,
    const float* __restrict__ wTq, const float* __restrict__ wTk,
    const float* __restrict__ wTv,
    const float* __restrict__ qb, const float* __restrict__ kb,
    const float* __restrict__ vb,
    float* __restrict__ q, float* __restrict__ kpad, float* __restrict__ vpad)
{
    __shared__ float sx[128 * 32];
    int bid = blockIdx.x;
    int osplit = bid & 1;
    int tile = (bid >> 1) % 98;
    int b = bid / 196;
    int pix0 = tile * 32;
    const float* xb = x + b * CHW + pix0;

    for (int i = threadIdx.x; i < 128 * 8; i += 256) {
        int c = i >> 3, p4 = (i & 7) * 4;
        *(float4*)(sx + c * 32 + p4) = *(const float4*)(xb + c * NPIX + p4);
    }
    __syncthreads();

    int xg = threadIdx.x & 15, og = threadIdx.x >> 4;
    int o0 = osplit * 64 + og * 4;
    const float* sxp = sx + xg * 2;

    float aq[4][2] = {}, ak[4][2] = {}, av[4][2] = {};
    #pragma unroll 2
    for (int c = 0; c < 128; ++c) {
        float4 wq4 = *(const float4*)(wTq + c * 128 + o0);
        float4 wk4 = *(const float4*)(wTk + c * 128 + o0);
        float4 wv4 = *(const float4*)(wTv + c * 128 + o0);
        float x0 = sxp[c * 32], x1 = sxp[c * 32 + 1];
        float wqr[4] = {wq4.x, wq4.y, wq4.z, wq4.w};
        float wkr[4] = {wk4.x, wk4.y, wk4.z, wk4.w};
        float wvr[4] = {wv4.x, wv4.y, wv4.z, wv4.w};
        #pragma unroll
        for (int oi = 0; oi < 4; ++oi) {
            aq[oi][0] += wqr[oi] * x0; aq[oi][1] += wqr[oi] * x1;
            ak[oi][0] += wkr[oi] * x0; ak[oi][1] += wkr[oi] * x1;
            av[oi][0] += wvr[oi] * x0; av[oi][1] += wvr[oi] * x1;
        }
    }
    int pp0 = pix0 + xg * 2;
    int yy0 = pp0 / 56, xx0 = pp0 - yy0 * 56;
    int pp1 = pp0 + 1;
    int yy1 = pp1 / 56, xx1 = pp1 - yy1 * 56;
    int po0 = (yy0 + 3) * 62 + xx0 + 3;
    int po1 = (yy1 + 3) * 62 + xx1 + 3;
    #pragma unroll
    for (int oi = 0; oi < 4; ++oi) {
        int o = o0 + oi;
        float bq = qb[o], bk = kb[o], bv = vb[o];
        float2 qv2 = {aq[oi][0] + bq, aq[oi][1] + bq};
        *(float2*)(q + b * CHW + o * NPIX + pp0) = qv2;
        float* kdst = kpad + (size_t)b * CPHW + (size_t)o * NPPIX;
        float* vdst = vpad + (size_t)b * CPHW + (size_t)o * NPPIX;
        kdst[po0] = ak[oi][0] + bk; kdst[po1] = ak[oi][1] + bk;
        vdst[po0] = av[oi][0] + bv; vdst[po1] = av[oi][1] + bv;
    }
}

// ---------------- attn: per-(b,c,row-quarter) local attention --------------
// 49 groups/quarter; wave owns groups wave,wave+4,...
// DS per group: ~8 read2(K) + 1 write(w) + 7 read2(w) + 7 read2(V) + 2 shfl.
__global__ __launch_bounds__(256) void attn_kernel(
    const float* __restrict__ q, const float* __restrict__ kpad,
    const float* __restrict__ vpad, const float* __restrict__ rb,
    float* __restrict__ out)
{
    __shared__ float sK[20 * SKS];
    __shared__ float sV[21 * SKS];   // row 20 zeroed (read only with w=0)
    __shared__ float sW[4 * 64];
    int bid = blockIdx.x;
    int qpart = bid & 3;
    int bc = bid >> 2;
    const float* qc = q + bc * NPIX + 784 * qpart;
    const float* kc = kpad + (size_t)bc * NPPIX + (14 * qpart) * 62;
    const float* vc = vpad + (size_t)bc * NPPIX + (14 * qpart) * 62;
    float* oc = out + bc * NPIX + 784 * qpart;

    for (int i = threadIdx.x; i < 20 * 62; i += 256) {
        int yy = i / 62, xx = i - yy * 62;
        sK[yy * SKS + xx] = kc[i];
        sV[yy * SKS + xx] = vc[i];
    }
    for (int i = threadIdx.x; i < SKS; i += 256) sV[20 * SKS + i] = 0.f;
    __syncthreads();

    int lane = threadIdx.x & 63;
    int wave = threadIdx.x >> 6;
    int k2 = min(lane, 48);
    int di = k2 / 7, dj = k2 - di * 7;
    float rbias = rb[di] + rb[7 + dj];
    int koff = di * SKS + dj;
    int t16 = lane & 15, p = lane >> 4;
    float* sWw = sW + wave * 64;

    for (int gl = wave; gl < 49; gl += 4) {
        int ul0 = gl * 16;
        int y0 = ul0 / 56;
        int x0 = ul0 - y0 * 56;

        // --- q: wave-uniform scalar loads (K$-hot), all 16 in SGPRs ------
        int ulu = __builtin_amdgcn_readfirstlane(ul0);
        float4 q0 = *(const float4*)(qc + ulu);
        float4 q1 = *(const float4*)(qc + ulu + 4);
        float4 q2 = *(const float4*)(qc + ulu + 8);
        float4 q3 = *(const float4*)(qc + ulu + 12);
        float qa[16] = {q0.x, q0.y, q0.z, q0.w, q1.x, q1.y, q1.z, q1.w,
                        q2.x, q2.y, q2.z, q2.w, q3.x, q3.y, q3.z, q3.w};
        float qs = 0.f;
        #pragma unroll
        for (int t = 0; t < 16; ++t) qs += qa[t];

        // --- qk: compile-time-offset LDS reads (merge into ds_read2) -----
        float acc = 0.f;
        const float* kb_ = sK + y0 * SKS + x0 + koff;
        if (x0 != 48) {
            #pragma unroll
            for (int t = 0; t < 16; ++t) acc += qa[t] * kb_[t];
        } else {
            const float* kb2 = sK + (y0 + 1) * SKS + koff;
            #pragma unroll
            for (int t = 0; t < 8; ++t) acc += qa[t] * kb_[t];
            #pragma unroll
            for (int t = 0; t < 8; ++t) acc += qa[8 + t] * kb2[t];
        }
        float val = (lane < 49) ? (acc + qs * rbias) : -1e30f;

        // --- softmax over 49 via DPP (VALU pipe) -------------------------
        float mS = wave_max(val);
        float e = __expf(val - mS);
        float sS = wave_sum(e);
        float wgt = e * __builtin_amdgcn_rcpf(sS);
        sWw[lane] = wgt;                       // lanes 49..63 write 0 pad

        // --- PV: lane = (t, ki-row-pair p); compile-time offsets ---------
        int u = ul0 + t16;
        int yt = u / 56;
        int xt = u - yt * 56;
        const float* vbase = sV + yt * SKS + xt + p * (2 * SKS);
        const float* wbase = sWw + p * 14;
        float oacc = 0.f;
        #pragma unroll
        for (int j = 0; j < 7; ++j) oacc += wbase[j] * vbase[j];
        #pragma unroll
        for (int j = 0; j < 7; ++j) oacc += wbase[7 + j] * vbase[SKS + j];
        oacc += __shfl_xor(oacc, 16);
        oacc += __shfl_xor(oacc, 32);
        if (lane < 16) oc[ul0 + lane] = oacc;
    }
}

extern "C" void kernel_launch(void* const* d_in, const int* in_sizes, int n_in,
                              void* d_out, int out_size, void* d_ws, size_t ws_size,
                              hipStream_t stream) {
    const float* x     = (const float*)d_in[0];
    const float* qw    = (const float*)d_in[1];
    const float* qb    = (const float*)d_in[2];
    const float* kw    = (const float*)d_in[3];
    const float* kb    = (const float*)d_in[4];
    const float* vw    = (const float*)d_in[5];
    const float* vb    = (const float*)d_in[6];
    const float* rel_h = (const float*)d_in[7];
    const float* rel_w = (const float*)d_in[8];
    float* out = (float*)d_out;

    float* ws   = (float*)d_ws;
    float* kpad = ws;                    // 1968128
    float* vpad = kpad + KPAD_N;         // 1968128
    float* qbuf = vpad + KPAD_N;         // 1605632
    float* wTq  = qbuf + 1605632;        // 16384
    float* wTk  = wTq + 16384;
    float* wTv  = wTk + 16384;
    float* rb   = wTv + 16384;           // 16

    prep_kernel<<<1416, 256, 0, stream>>>(qw, kw, vw, kb, vb, rel_h, rel_w,
                                          kpad, vpad, wTq, wTk, wTv, rb);
    conv_kernel<<<784, 256, 0, stream>>>(x, wTq, wTk, wTv, qb, kb, vb,
                                         qbuf, kpad, vpad);
    attn_kernel<<<2048, 256, 0, stream>>>(qbuf, kpad, vpad, rb, out);
}

// Round 5
// 87.865 us; speedup vs baseline: 1.6551x; 1.2055x over previous
//
#include <hip/hip_runtime.h>
#include <hip/hip_bf16.h>
#include <math.h>

#define NB    4
#define NC    128
#define NPIX  3136      // 56*56
#define NPPIX 3844      // 62*62
#define CHW   401408    // 128*3136
#define CPHW  492032    // 128*3844
#define KPAD_N 1968128  // 4*128*3844
#define SKS   68        // padded LDS row stride for K/V images

// ---------- DPP wave64 reduce helpers (VALU pipe, no DS) -------------------
template <int CTRL, int RM>
__device__ __forceinline__ float dpp_mov(float x, float old) {
    return __int_as_float(__builtin_amdgcn_update_dpp(
        __float_as_int(old), __float_as_int(x), CTRL, RM, 0xf, false));
}
__device__ __forceinline__ float wave_max(float x) {
    x = fmaxf(x, dpp_mov<0x111, 0xf>(x, x));   // row_shr:1
    x = fmaxf(x, dpp_mov<0x112, 0xf>(x, x));   // row_shr:2
    x = fmaxf(x, dpp_mov<0x114, 0xf>(x, x));   // row_shr:4
    x = fmaxf(x, dpp_mov<0x118, 0xf>(x, x));   // row_shr:8
    x = fmaxf(x, dpp_mov<0x142, 0xa>(x, x));   // row_bcast:15 -> rows 1,3
    x = fmaxf(x, dpp_mov<0x143, 0xc>(x, x));   // row_bcast:31 -> rows 2,3
    return __int_as_float(__builtin_amdgcn_readlane(__float_as_int(x), 63));
}
__device__ __forceinline__ float wave_sum(float x) {
    x = x + dpp_mov<0x111, 0xf>(x, 0.f);
    x = x + dpp_mov<0x112, 0xf>(x, 0.f);
    x = x + dpp_mov<0x114, 0xf>(x, 0.f);
    x = x + dpp_mov<0x118, 0xf>(x, 0.f);
    x = x + dpp_mov<0x142, 0xa>(x, 0.f);
    x = x + dpp_mov<0x143, 0xc>(x, 0.f);
    return __int_as_float(__builtin_amdgcn_readlane(__float_as_int(x), 63));
}

// ---------------- prep: halo bias-fill + weight pack + rel sums ------------
// Weight pack: W4[c4][o][cc] (float4 per (c4,o)) so lane=o loads are coalesced.
__global__ __launch_bounds__(256) void prep_kernel(
    const float* __restrict__ qw, const float* __restrict__ kw,
    const float* __restrict__ vw,
    const float* __restrict__ kb, const float* __restrict__ vb,
    const float* __restrict__ rel_h, const float* __restrict__ rel_w,
    float* __restrict__ kpad, float* __restrict__ vpad,
    float* __restrict__ w4q, float* __restrict__ w4k, float* __restrict__ w4v,
    float* __restrict__ rb)
{
    int idx = blockIdx.x * 256 + threadIdx.x;
    {   // halo fill: 708 positions per image, 512 images
        int img = idx / 708;
        int hl = idx - img * 708;
        int p;
        if (hl < 186) p = hl;                           // rows 0..2
        else if (hl < 372) p = 3658 + (hl - 186);       // rows 59..61
        else {
            int j = hl - 372;
            int r = j / 6, cc = j - r * 6;
            p = (r + 3) * 62 + (cc < 3 ? cc : cc + 56); // cols 0-2, 59-61
        }
        int ch = img & 127;
        size_t o = (size_t)img * NPPIX + p;
        kpad[o] = kb[ch];
        vpad[o] = vb[ch];
    }
    if (idx < 3 * 16384) {
        int m = idx >> 14;
        int r = idx & 16383;          // dst-linear: ((c4*128 + o)*4 + cc)
        int cc = r & 3;
        int t = r >> 2;
        int o = t & 127;
        int c4 = t >> 7;
        const float* src = (m == 0) ? qw : (m == 1) ? kw : vw;
        float* dst = (m == 0) ? w4q : (m == 1) ? w4k : w4v;
        dst[r] = src[o * 128 + c4 * 4 + cc];
    }
    if (idx < 14) {
        const float* src = (idx < 7) ? rel_h : rel_w;
        int off = (idx < 7) ? idx : idx - 7;
        float s = 0.f;
        for (int c = 0; c < 64; ++c) s += src[c * 7 + off];
        rb[idx] = s;
    }
}

// ---------------- conv: fused 1x1 convs Q,K,V (fp32, lane = out-channel) ---
// block = (b, 16-pixel tile). 4 waves = 2 o-halves x 2 pixel-halves.
// lane owns one o; weights via coalesced packed-W4 dwordx4; x via LDS bcast.
__global__ __launch_bounds__(256) void conv_kernel(
    const float* __restrict__ x,
    const float* __restrict__ w4q, const float* __restrict__ w4k,
    const float* __restrict__ w4v,
    const float* __restrict__ qb, const float* __restrict__ kb,
    const float* __restrict__ vb,
    float* __restrict__ q, float* __restrict__ kpad, float* __restrict__ vpad)
{
    __shared__ float sx[128 * 16];   // [c][pix] 8KB
    int bid = blockIdx.x;
    int tile = bid % 196;
    int b = bid / 196;
    int pix0 = tile * 16;
    const float* xb = x + b * CHW + pix0;

    for (int i = threadIdx.x; i < 512; i += 256) {
        int c = i >> 2, p4 = (i & 3) * 4;
        *(float4*)(sx + c * 16 + p4) = *(const float4*)(xb + c * NPIX + p4);
    }
    __syncthreads();

    int lane = threadIdx.x & 63;
    int wave = threadIdx.x >> 6;
    int ohalf = wave & 1;
    int ph8 = (wave >> 1) * 8;
    int o = ohalf * 64 + lane;
    const float4* Wq = (const float4*)w4q + o;
    const float4* Wk = (const float4*)w4k + o;
    const float4* Wv = (const float4*)w4v + o;

    float aq[8] = {}, ak[8] = {}, av[8] = {};
    #pragma unroll 2
    for (int c4 = 0; c4 < 32; ++c4) {
        float4 wq4 = Wq[c4 * 128];
        float4 wk4 = Wk[c4 * 128];
        float4 wv4 = Wv[c4 * 128];
        float wqr[4] = {wq4.x, wq4.y, wq4.z, wq4.w};
        float wkr[4] = {wk4.x, wk4.y, wk4.z, wk4.w};
        float wvr[4] = {wv4.x, wv4.y, wv4.z, wv4.w};
        #pragma unroll
        for (int cc = 0; cc < 4; ++cc) {
            const float* xr = sx + (c4 * 4 + cc) * 16 + ph8;
            float4 xa = *(const float4*)xr;
            float4 xc = *(const float4*)(xr + 4);
            float xv[8] = {xa.x, xa.y, xa.z, xa.w, xc.x, xc.y, xc.z, xc.w};
            #pragma unroll
            for (int p = 0; p < 8; ++p) {
                aq[p] += wqr[cc] * xv[p];
                ak[p] += wkr[cc] * xv[p];
                av[p] += wvr[cc] * xv[p];
            }
        }
    }
    float bq = qb[o], bk = kb[o], bv = vb[o];
    float* qdst = q + b * CHW + o * NPIX + pix0 + ph8;
    float4 q0 = {aq[0] + bq, aq[1] + bq, aq[2] + bq, aq[3] + bq};
    float4 q1 = {aq[4] + bq, aq[5] + bq, aq[6] + bq, aq[7] + bq};
    *(float4*)qdst = q0;
    *(float4*)(qdst + 4) = q1;
    float* kdst = kpad + (size_t)b * CPHW + (size_t)o * NPPIX;
    float* vdst = vpad + (size_t)b * CPHW + (size_t)o * NPPIX;
    #pragma unroll
    for (int j = 0; j < 8; ++j) {
        int pp = pix0 + ph8 + j;
        int yy = pp / 56, xx = pp - yy * 56;
        int po = (yy + 3) * 62 + xx + 3;
        kdst[po] = ak[j] + bk;
        vdst[po] = av[j] + bv;
    }
}

// ---------------- attn: per-(b,c,row-quarter) local attention --------------
// 49 groups/quarter; wave owns groups wave,wave+4,...
__global__ __launch_bounds__(256) void attn_kernel(
    const float* __restrict__ q, const float* __restrict__ kpad,
    const float* __restrict__ vpad, const float* __restrict__ rb,
    float* __restrict__ out)
{
    __shared__ float sK[20 * SKS];
    __shared__ float sV[21 * SKS];   // row 20 zeroed (read only with w=0)
    __shared__ float sW[4 * 64];
    int bid = blockIdx.x;
    int qpart = bid & 3;
    int bc = bid >> 2;
    const float* qc = q + bc * NPIX + 784 * qpart;
    const float* kc = kpad + (size_t)bc * NPPIX + (14 * qpart) * 62;
    const float* vc = vpad + (size_t)bc * NPPIX + (14 * qpart) * 62;
    float* oc = out + bc * NPIX + 784 * qpart;

    for (int i = threadIdx.x; i < 20 * 62; i += 256) {
        int yy = i / 62, xx = i - yy * 62;
        sK[yy * SKS + xx] = kc[i];
        sV[yy * SKS + xx] = vc[i];
    }
    for (int i = threadIdx.x; i < SKS; i += 256) sV[20 * SKS + i] = 0.f;
    __syncthreads();

    int lane = threadIdx.x & 63;
    int wave = threadIdx.x >> 6;
    int k2 = min(lane, 48);
    int di = k2 / 7, dj = k2 - di * 7;
    float rbias = rb[di] + rb[7 + dj];
    int koff = di * SKS + dj;
    int t16 = lane & 15, p = lane >> 4;
    float* sWw = sW + wave * 64;

    for (int gl = wave; gl < 49; gl += 4) {
        int ul0 = gl * 16;
        int y0 = ul0 / 56;
        int x0 = ul0 - y0 * 56;

        // --- q: wave-uniform scalar loads (K$-hot), all 16 in SGPRs ------
        int ulu = __builtin_amdgcn_readfirstlane(ul0);
        float4 q0 = *(const float4*)(qc + ulu);
        float4 q1 = *(const float4*)(qc + ulu + 4);
        float4 q2 = *(const float4*)(qc + ulu + 8);
        float4 q3 = *(const float4*)(qc + ulu + 12);
        float qa[16] = {q0.x, q0.y, q0.z, q0.w, q1.x, q1.y, q1.z, q1.w,
                        q2.x, q2.y, q2.z, q2.w, q3.x, q3.y, q3.z, q3.w};
        float qs = 0.f;
        #pragma unroll
        for (int t = 0; t < 16; ++t) qs += qa[t];

        // --- qk: compile-time-offset LDS reads (merge into ds_read2) -----
        float acc = 0.f;
        const float* kb_ = sK + y0 * SKS + x0 + koff;
        if (x0 != 48) {
            #pragma unroll
            for (int t = 0; t < 16; ++t) acc += qa[t] * kb_[t];
        } else {
            const float* kb2 = sK + (y0 + 1) * SKS + koff;
            #pragma unroll
            for (int t = 0; t < 8; ++t) acc += qa[t] * kb_[t];
            #pragma unroll
            for (int t = 0; t < 8; ++t) acc += qa[8 + t] * kb2[t];
        }
        float val = (lane < 49) ? (acc + qs * rbias) : -1e30f;

        // --- softmax over 49 via DPP (VALU pipe) -------------------------
        float mS = wave_max(val);
        float e = __expf(val - mS);
        float sS = wave_sum(e);
        float wgt = e * __builtin_amdgcn_rcpf(sS);
        sWw[lane] = wgt;                       // lanes 49..63 write 0 pad

        // --- PV: lane = (t, ki-row-pair p); compile-time offsets ---------
        int u = ul0 + t16;
        int yt = u / 56;
        int xt = u - yt * 56;
        const float* vbase = sV + yt * SKS + xt + p * (2 * SKS);
        const float* wbase = sWw + p * 14;
        float oacc = 0.f;
        #pragma unroll
        for (int j = 0; j < 7; ++j) oacc += wbase[j] * vbase[j];
        #pragma unroll
        for (int j = 0; j < 7; ++j) oacc += wbase[7 + j] * vbase[SKS + j];
        oacc += __shfl_xor(oacc, 16);
        oacc += __shfl_xor(oacc, 32);
        if (lane < 16) oc[ul0 + lane] = oacc;
    }
}

extern "C" void kernel_launch(void* const* d_in, const int* in_sizes, int n_in,
                              void* d_out, int out_size, void* d_ws, size_t ws_size,
                              hipStream_t stream) {
    const float* x     = (const float*)d_in[0];
    const float* qw    = (const float*)d_in[1];
    const float* qb    = (const float*)d_in[2];
    const float* kw    = (const float*)d_in[3];
    const float* kb    = (const float*)d_in[4];
    const float* vw    = (const float*)d_in[5];
    const float* vb    = (const float*)d_in[6];
    const float* rel_h = (const float*)d_in[7];
    const float* rel_w = (const float*)d_in[8];
    float* out = (float*)d_out;

    float* ws   = (float*)d_ws;
    float* kpad = ws;                    // 1968128
    float* vpad = kpad + KPAD_N;         // 1968128
    float* qbuf = vpad + KPAD_N;         // 1605632
    float* w4q  = qbuf + 1605632;        // 16384
    float* w4k  = w4q + 16384;
    float* w4v  = w4k + 16384;
    float* rb   = w4v + 16384;           // 16

    prep_kernel<<<1416, 256, 0, stream>>>(qw, kw, vw, kb, vb, rel_h, rel_w,
                                          kpad, vpad, w4q, w4k, w4v, rb);
    conv_kernel<<<784, 256, 0, stream>>>(x, w4q, w4k, w4v, qb, kb, vb,
                                         qbuf, kpad, vpad);
    attn_kernel<<<2048, 256, 0, stream>>>(qbuf, kpad, vpad, rb, out);
}

// Round 6
// 72.596 us; speedup vs baseline: 2.0032x; 1.2103x over previous
//
#include <hip/hip_runtime.h>
#include <hip/hip_bf16.h>
#include <math.h>

#define NB    4
#define NC    128
#define NPIX  3136      // 56*56
#define NPPIX 3844      // 62*62
#define CHW   401408    // 128*3136
#define CPHW  492032    // 128*3844
#define KPAD_N 1968128  // 4*128*3844
#define SKS   68        // padded LDS row stride for K/V images

// ---------- DPP wave64 reduce helpers (VALU pipe, no DS) -------------------
template <int CTRL, int RM>
__device__ __forceinline__ float dpp_mov(float x, float old) {
    return __int_as_float(__builtin_amdgcn_update_dpp(
        __float_as_int(old), __float_as_int(x), CTRL, RM, 0xf, false));
}
__device__ __forceinline__ float wave_max(float x) {
    x = fmaxf(x, dpp_mov<0x111, 0xf>(x, x));   // row_shr:1
    x = fmaxf(x, dpp_mov<0x112, 0xf>(x, x));   // row_shr:2
    x = fmaxf(x, dpp_mov<0x114, 0xf>(x, x));   // row_shr:4
    x = fmaxf(x, dpp_mov<0x118, 0xf>(x, x));   // row_shr:8
    x = fmaxf(x, dpp_mov<0x142, 0xa>(x, x));   // row_bcast:15 -> rows 1,3
    x = fmaxf(x, dpp_mov<0x143, 0xc>(x, x));   // row_bcast:31 -> rows 2,3
    return __int_as_float(__builtin_amdgcn_readlane(__float_as_int(x), 63));
}
__device__ __forceinline__ float wave_sum(float x) {
    x = x + dpp_mov<0x111, 0xf>(x, 0.f);
    x = x + dpp_mov<0x112, 0xf>(x, 0.f);
    x = x + dpp_mov<0x114, 0xf>(x, 0.f);
    x = x + dpp_mov<0x118, 0xf>(x, 0.f);
    x = x + dpp_mov<0x142, 0xa>(x, 0.f);
    x = x + dpp_mov<0x143, 0xc>(x, 0.f);
    return __int_as_float(__builtin_amdgcn_readlane(__float_as_int(x), 63));
}

// ---------------- prep: halo bias-fill + weight pack + rel sums ------------
// Weight pack: W4[c4][o][cc] (float4 per (c4,o)) so lane=o loads are coalesced.
__global__ __launch_bounds__(256) void prep_kernel(
    const float* __restrict__ qw, const float* __restrict__ kw,
    const float* __restrict__ vw,
    const float* __restrict__ kb, const float* __restrict__ vb,
    const float* __restrict__ rel_h, const float* __restrict__ rel_w,
    float* __restrict__ kpad, float* __restrict__ vpad,
    float* __restrict__ w4q, float* __restrict__ w4k, float* __restrict__ w4v,
    float* __restrict__ rb)
{
    int idx = blockIdx.x * 256 + threadIdx.x;
    {   // halo fill: 708 positions per image, 512 images
        int img = idx / 708;
        int hl = idx - img * 708;
        int p;
        if (hl < 186) p = hl;                           // rows 0..2
        else if (hl < 372) p = 3658 + (hl - 186);       // rows 59..61
        else {
            int j = hl - 372;
            int r = j / 6, cc = j - r * 6;
            p = (r + 3) * 62 + (cc < 3 ? cc : cc + 56); // cols 0-2, 59-61
        }
        int ch = img & 127;
        size_t o = (size_t)img * NPPIX + p;
        kpad[o] = kb[ch];
        vpad[o] = vb[ch];
    }
    if (idx < 3 * 16384) {
        int m = idx >> 14;
        int r = idx & 16383;          // dst-linear: ((c4*128 + o)*4 + cc)
        int cc = r & 3;
        int t = r >> 2;
        int o = t & 127;
        int c4 = t >> 7;
        const float* src = (m == 0) ? qw : (m == 1) ? kw : vw;
        float* dst = (m == 0) ? w4q : (m == 1) ? w4k : w4v;
        dst[r] = src[o * 128 + c4 * 4 + cc];
    }
    if (idx < 14) {
        const float* src = (idx < 7) ? rel_h : rel_w;
        int off = (idx < 7) ? idx : idx - 7;
        float s = 0.f;
        for (int c = 0; c < 64; ++c) s += src[c * 7 + off];
        rb[idx] = s;
    }
}

// ---------------- conv: fused 1x1 convs Q,K,V (fp32) -----------------------
// block = (b, 16-pixel tile). 4 waves; lane -> o = wave*32+(lane&31),
// pixel-half = (lane>>5)*8. Compute lane=o (coalesced W4 loads, x via LDS
// broadcast); store via stride-18 LDS transpose so lane=pixel (coalesced).
__global__ __launch_bounds__(256) void conv_kernel(
    const float* __restrict__ x,
    const float* __restrict__ w4q, const float* __restrict__ w4k,
    const float* __restrict__ w4v,
    const float* __restrict__ qb, const float* __restrict__ kb,
    const float* __restrict__ vb,
    float* __restrict__ q, float* __restrict__ kpad, float* __restrict__ vpad)
{
    __shared__ float sx[128 * 16];   // [c][pix] 8KB
    __shared__ float st[128 * 18];   // transpose buffer [o][pix], stride 18
    int bid = blockIdx.x;
    int tile = bid % 196;
    int b = bid / 196;
    int pix0 = tile * 16;
    const float* xb = x + b * CHW + pix0;

    for (int i = threadIdx.x; i < 512; i += 256) {
        int c = i >> 2, p4 = (i & 3) * 4;
        *(float4*)(sx + c * 16 + p4) = *(const float4*)(xb + c * NPIX + p4);
    }
    __syncthreads();

    int lane = threadIdx.x & 63;
    int wave = threadIdx.x >> 6;
    int o = wave * 32 + (lane & 31);
    int ph = (lane >> 5) * 8;
    const float4* Wq = (const float4*)w4q + o;
    const float4* Wk = (const float4*)w4k + o;
    const float4* Wv = (const float4*)w4v + o;

    float aq[8] = {}, ak[8] = {}, av[8] = {};
    #pragma unroll 2
    for (int c4 = 0; c4 < 32; ++c4) {
        float4 wq4 = Wq[c4 * 128];
        float4 wk4 = Wk[c4 * 128];
        float4 wv4 = Wv[c4 * 128];
        float wqr[4] = {wq4.x, wq4.y, wq4.z, wq4.w};
        float wkr[4] = {wk4.x, wk4.y, wk4.z, wk4.w};
        float wvr[4] = {wv4.x, wv4.y, wv4.z, wv4.w};
        #pragma unroll
        for (int cc = 0; cc < 4; ++cc) {
            const float* xr = sx + (c4 * 4 + cc) * 16 + ph;
            float4 xa = *(const float4*)xr;
            float4 xc = *(const float4*)(xr + 4);
            float xv[8] = {xa.x, xa.y, xa.z, xa.w, xc.x, xc.y, xc.z, xc.w};
            #pragma unroll
            for (int p = 0; p < 8; ++p) {
                aq[p] += wqr[cc] * xv[p];
                ak[p] += wkr[cc] * xv[p];
                av[p] += wvr[cc] * xv[p];
            }
        }
    }
    float bq = qb[o], bk = kb[o], bv = vb[o];

    // per-thread store-side indices (lane = pixel)
    int pix = threadIdx.x & 15;
    int o8 = (threadIdx.x >> 4) * 8;
    int pp = pix0 + pix;
    int yy = pp / 56, xx = pp - yy * 56;
    int po = (yy + 3) * 62 + xx + 3;
    float* wr = st + o * 18 + ph;

    // ---- Q ----
    {
        #pragma unroll
        for (int p = 0; p < 8; ++p) wr[p] = aq[p] + bq;
        __syncthreads();
        float* qd = q + b * CHW + pix0 + pix;
        #pragma unroll
        for (int i = 0; i < 8; ++i)
            qd[(o8 + i) * NPIX] = st[(o8 + i) * 18 + pix];
    }
    // ---- K ----
    {
        __syncthreads();
        #pragma unroll
        for (int p = 0; p < 8; ++p) wr[p] = ak[p] + bk;
        __syncthreads();
        float* kd = kpad + (size_t)b * CPHW + po;
        #pragma unroll
        for (int i = 0; i < 8; ++i)
            kd[(size_t)(o8 + i) * NPPIX] = st[(o8 + i) * 18 + pix];
    }
    // ---- V ----
    {
        __syncthreads();
        #pragma unroll
        for (int p = 0; p < 8; ++p) wr[p] = av[p] + bv;
        __syncthreads();
        float* vd = vpad + (size_t)b * CPHW + po;
        #pragma unroll
        for (int i = 0; i < 8; ++i)
            vd[(size_t)(o8 + i) * NPPIX] = st[(o8 + i) * 18 + pix];
    }
}

// ---------------- attn: per-(b,c,row-quarter) local attention --------------
// 49 groups/quarter; wave owns groups wave,wave+4,...
__global__ __launch_bounds__(256) void attn_kernel(
    const float* __restrict__ q, const float* __restrict__ kpad,
    const float* __restrict__ vpad, const float* __restrict__ rb,
    float* __restrict__ out)
{
    __shared__ float sK[20 * SKS];
    __shared__ float sV[21 * SKS];   // row 20 zeroed (read only with w=0)
    __shared__ float sW[4 * 64];
    int bid = blockIdx.x;
    int qpart = bid & 3;
    int bc = bid >> 2;
    const float* qc = q + bc * NPIX + 784 * qpart;
    const float* kc = kpad + (size_t)bc * NPPIX + (14 * qpart) * 62;
    const float* vc = vpad + (size_t)bc * NPPIX + (14 * qpart) * 62;
    float* oc = out + bc * NPIX + 784 * qpart;

    for (int i = threadIdx.x; i < 20 * 62; i += 256) {
        int yy = i / 62, xx = i - yy * 62;
        sK[yy * SKS + xx] = kc[i];
        sV[yy * SKS + xx] = vc[i];
    }
    for (int i = threadIdx.x; i < SKS; i += 256) sV[20 * SKS + i] = 0.f;
    __syncthreads();

    int lane = threadIdx.x & 63;
    int wave = threadIdx.x >> 6;
    int k2 = min(lane, 48);
    int di = k2 / 7, dj = k2 - di * 7;
    float rbias = rb[di] + rb[7 + dj];
    int koff = di * SKS + dj;
    int t16 = lane & 15, p = lane >> 4;
    float* sWw = sW + wave * 64;

    for (int gl = wave; gl < 49; gl += 4) {
        int ul0 = gl * 16;
        int y0 = ul0 / 56;
        int x0 = ul0 - y0 * 56;

        // --- q: wave-uniform scalar loads (K$-hot), all 16 in SGPRs ------
        int ulu = __builtin_amdgcn_readfirstlane(ul0);
        float4 q0 = *(const float4*)(qc + ulu);
        float4 q1 = *(const float4*)(qc + ulu + 4);
        float4 q2 = *(const float4*)(qc + ulu + 8);
        float4 q3 = *(const float4*)(qc + ulu + 12);
        float qa[16] = {q0.x, q0.y, q0.z, q0.w, q1.x, q1.y, q1.z, q1.w,
                        q2.x, q2.y, q2.z, q2.w, q3.x, q3.y, q3.z, q3.w};
        float qs = 0.f;
        #pragma unroll
        for (int t = 0; t < 16; ++t) qs += qa[t];

        // --- qk: compile-time-offset LDS reads (merge into ds_read2) -----
        float acc = 0.f;
        const float* kb_ = sK + y0 * SKS + x0 + koff;
        if (x0 != 48) {
            #pragma unroll
            for (int t = 0; t < 16; ++t) acc += qa[t] * kb_[t];
        } else {
            const float* kb2 = sK + (y0 + 1) * SKS + koff;
            #pragma unroll
            for (int t = 0; t < 8; ++t) acc += qa[t] * kb_[t];
            #pragma unroll
            for (int t = 0; t < 8; ++t) acc += qa[8 + t] * kb2[t];
        }
        float val = (lane < 49) ? (acc + qs * rbias) : -1e30f;

        // --- softmax over 49 via DPP (VALU pipe) -------------------------
        float mS = wave_max(val);
        float e = __expf(val - mS);
        float sS = wave_sum(e);
        float wgt = e * __builtin_amdgcn_rcpf(sS);
        sWw[lane] = wgt;                       // lanes 49..63 write 0 pad

        // --- PV: lane = (t, ki-row-pair p); compile-time offsets ---------
        int u = ul0 + t16;
        int yt = u / 56;
        int xt = u - yt * 56;
        const float* vbase = sV + yt * SKS + xt + p * (2 * SKS);
        const float* wbase = sWw + p * 14;
        float oacc = 0.f;
        #pragma unroll
        for (int j = 0; j < 7; ++j) oacc += wbase[j] * vbase[j];
        #pragma unroll
        for (int j = 0; j < 7; ++j) oacc += wbase[7 + j] * vbase[SKS + j];
        oacc += __shfl_xor(oacc, 16);
        oacc += __shfl_xor(oacc, 32);
        if (lane < 16) oc[ul0 + lane] = oacc;
    }
}

extern "C" void kernel_launch(void* const* d_in, const int* in_sizes, int n_in,
                              void* d_out, int out_size, void* d_ws, size_t ws_size,
                              hipStream_t stream) {
    const float* x     = (const float*)d_in[0];
    const float* qw    = (const float*)d_in[1];
    const float* qb    = (const float*)d_in[2];
    const float* kw    = (const float*)d_in[3];
    const float* kb    = (const float*)d_in[4];
    const float* vw    = (const float*)d_in[5];
    const float* vb    = (const float*)d_in[6];
    const float* rel_h = (const float*)d_in[7];
    const float* rel_w = (const float*)d_in[8];
    float* out = (float*)d_out;

    float* ws   = (float*)d_ws;
    float* kpad = ws;                    // 1968128
    float* vpad = kpad + KPAD_N;         // 1968128
    float* qbuf = vpad + KPAD_N;         // 1605632
    float* w4q  = qbuf + 1605632;        // 16384
    float* w4k  = w4q + 16384;
    float* w4v  = w4k + 16384;
    float* rb   = w4v + 16384;           // 16

    prep_kernel<<<1416, 256, 0, stream>>>(qw, kw, vw, kb, vb, rel_h, rel_w,
                                          kpad, vpad, w4q, w4k, w4v, rb);
    conv_kernel<<<784, 256, 0, stream>>>(x, w4q, w4k, w4v, qb, kb, vb,
                                         qbuf, kpad, vpad);
    attn_kernel<<<2048, 256, 0, stream>>>(qbuf, kpad, vpad, rb, out);
}

// Round 7
// 72.239 us; speedup vs baseline: 2.0131x; 1.0049x over previous
//
#include <hip/hip_runtime.h>
#include <hip/hip_bf16.h>
#include <math.h>

#define NB    4
#define NC    128
#define NPIX  3136      // 56*56
#define CHW   401408    // 128*3136
#define SKS   68        // padded LDS row stride for K/V images
#define STS   19        // conv transpose-buffer row stride (odd => bank-clean)

// ---------- DPP wave64 reduce helpers (VALU pipe, no DS) -------------------
template <int CTRL, int RM>
__device__ __forceinline__ float dpp_mov(float x, float old) {
    return __int_as_float(__builtin_amdgcn_update_dpp(
        __float_as_int(old), __float_as_int(x), CTRL, RM, 0xf, false));
}
__device__ __forceinline__ float wave_max(float x) {
    x = fmaxf(x, dpp_mov<0x111, 0xf>(x, x));   // row_shr:1
    x = fmaxf(x, dpp_mov<0x112, 0xf>(x, x));   // row_shr:2
    x = fmaxf(x, dpp_mov<0x114, 0xf>(x, x));   // row_shr:4
    x = fmaxf(x, dpp_mov<0x118, 0xf>(x, x));   // row_shr:8
    x = fmaxf(x, dpp_mov<0x142, 0xa>(x, x));   // row_bcast:15 -> rows 1,3
    x = fmaxf(x, dpp_mov<0x143, 0xc>(x, x));   // row_bcast:31 -> rows 2,3
    return __int_as_float(__builtin_amdgcn_readlane(__float_as_int(x), 63));
}
__device__ __forceinline__ float wave_sum(float x) {
    x = x + dpp_mov<0x111, 0xf>(x, 0.f);
    x = x + dpp_mov<0x112, 0xf>(x, 0.f);
    x = x + dpp_mov<0x114, 0xf>(x, 0.f);
    x = x + dpp_mov<0x118, 0xf>(x, 0.f);
    x = x + dpp_mov<0x142, 0xa>(x, 0.f);
    x = x + dpp_mov<0x143, 0xc>(x, 0.f);
    return __int_as_float(__builtin_amdgcn_readlane(__float_as_int(x), 63));
}

// ---------------- prep: weight pack + rel sums (no halo fill anymore) ------
// Weight pack: W4[c4][o][cc] (float4 per (c4,o)) so lane=o loads are coalesced.
__global__ __launch_bounds__(256) void prep_kernel(
    const float* __restrict__ qw, const float* __restrict__ kw,
    const float* __restrict__ vw,
    const float* __restrict__ rel_h, const float* __restrict__ rel_w,
    float* __restrict__ w4q, float* __restrict__ w4k, float* __restrict__ w4v,
    float* __restrict__ rb)
{
    int idx = blockIdx.x * 256 + threadIdx.x;
    if (idx < 3 * 16384) {
        int m = idx >> 14;
        int r = idx & 16383;          // dst-linear: ((c4*128 + o)*4 + cc)
        int cc = r & 3;
        int t = r >> 2;
        int o = t & 127;
        int c4 = t >> 7;
        const float* src = (m == 0) ? qw : (m == 1) ? kw : vw;
        float* dst = (m == 0) ? w4q : (m == 1) ? w4k : w4v;
        dst[r] = src[o * 128 + c4 * 4 + cc];
    }
    if (idx < 14) {
        const float* src = (idx < 7) ? rel_h : rel_w;
        int off = (idx < 7) ? idx : idx - 7;
        float s = 0.f;
        for (int c = 0; c < 64; ++c) s += src[c * 7 + off];
        rb[idx] = s;
    }
}

// ---------------- conv: fused 1x1 convs Q,K,V (fp32) -----------------------
// block = (b, 16-pixel tile). lane=o for compute (coalesced W4 loads with
// register prefetch, x via LDS broadcast); one 3-plane stride-19 LDS
// transpose, 2 barriers; lane=pixel stores to UNPADDED q/k/v.
__global__ __launch_bounds__(256) void conv_kernel(
    const float* __restrict__ x,
    const float* __restrict__ w4q, const float* __restrict__ w4k,
    const float* __restrict__ w4v,
    const float* __restrict__ qb, const float* __restrict__ kb,
    const float* __restrict__ vb,
    float* __restrict__ q, float* __restrict__ kbuf, float* __restrict__ vbuf)
{
    __shared__ float sx[128 * 16];       // [c][pix] 8KB
    __shared__ float st[3 * 128 * STS];  // q/k/v transpose planes, 28.5KB
    int bid = blockIdx.x;
    int tile = bid % 196;
    int b = bid / 196;
    int pix0 = tile * 16;
    const float* xb = x + b * CHW + pix0;

    for (int i = threadIdx.x; i < 512; i += 256) {
        int c = i >> 2, p4 = (i & 3) * 4;
        *(float4*)(sx + c * 16 + p4) = *(const float4*)(xb + c * NPIX + p4);
    }
    __syncthreads();

    int lane = threadIdx.x & 63;
    int wave = threadIdx.x >> 6;
    int o = wave * 32 + (lane & 31);
    int ph = (lane >> 5) * 8;
    const float4* Wq = (const float4*)w4q + o;
    const float4* Wk = (const float4*)w4k + o;
    const float4* Wv = (const float4*)w4v + o;

    float4 wqc = Wq[0], wkc = Wk[0], wvc = Wv[0];   // pipeline head
    float aq[8] = {}, ak[8] = {}, av[8] = {};
    #pragma unroll 1
    for (int c4 = 0; c4 < 32; ++c4) {
        float4 xs[8];
        #pragma unroll
        for (int cc = 0; cc < 4; ++cc) {
            xs[2 * cc]     = *(const float4*)(sx + (c4 * 4 + cc) * 16 + ph);
            xs[2 * cc + 1] = *(const float4*)(sx + (c4 * 4 + cc) * 16 + ph + 4);
        }
        float4 wq4 = wqc, wk4 = wkc, wv4 = wvc;
        if (c4 < 31) {   // prefetch next iter's weights (covered by FMAs)
            wqc = Wq[(c4 + 1) * 128];
            wkc = Wk[(c4 + 1) * 128];
            wvc = Wv[(c4 + 1) * 128];
        }
        float wqr[4] = {wq4.x, wq4.y, wq4.z, wq4.w};
        float wkr[4] = {wk4.x, wk4.y, wk4.z, wk4.w};
        float wvr[4] = {wv4.x, wv4.y, wv4.z, wv4.w};
        #pragma unroll
        for (int cc = 0; cc < 4; ++cc) {
            float4 xa = xs[2 * cc], xc = xs[2 * cc + 1];
            float xv[8] = {xa.x, xa.y, xa.z, xa.w, xc.x, xc.y, xc.z, xc.w};
            #pragma unroll
            for (int p = 0; p < 8; ++p) {
                aq[p] += wqr[cc] * xv[p];
                ak[p] += wkr[cc] * xv[p];
                av[p] += wvr[cc] * xv[p];
            }
        }
    }
    float bq = qb[o], bk = kb[o], bv = vb[o];
    float* wrq = st + o * STS + ph;
    float* wrk = st + 128 * STS + o * STS + ph;
    float* wrv = st + 2 * 128 * STS + o * STS + ph;
    #pragma unroll
    for (int p = 0; p < 8; ++p) {
        wrq[p] = aq[p] + bq;
        wrk[p] = ak[p] + bk;
        wrv[p] = av[p] + bv;
    }
    __syncthreads();

    int pix = threadIdx.x & 15;
    int o8 = (threadIdx.x >> 4) * 8;
    float* qd = q + b * CHW + pix0 + pix;
    float* kd = kbuf + b * CHW + pix0 + pix;
    float* vd = vbuf + b * CHW + pix0 + pix;
    #pragma unroll
    for (int i = 0; i < 8; ++i) {
        int r = o8 + i;
        qd[r * NPIX] = st[r * STS + pix];
        kd[r * NPIX] = st[128 * STS + r * STS + pix];
        vd[r * NPIX] = st[2 * 128 * STS + r * STS + pix];
    }
}

// ---------------- attn: per-(b,c,row-quarter) local attention --------------
// K/V staged from UNPADDED buffers; halo synthesized from bias scalars.
// q prefetched one group ahead (hides L2 latency under QK/softmax/PV).
__global__ __launch_bounds__(256) void attn_kernel(
    const float* __restrict__ q, const float* __restrict__ kbuf,
    const float* __restrict__ vbuf,
    const float* __restrict__ kb, const float* __restrict__ vb,
    const float* __restrict__ rb, float* __restrict__ out)
{
    __shared__ float sK[20 * SKS];
    __shared__ float sV[21 * SKS];   // row 20 zeroed (read only with w=0)
    __shared__ float sW[4 * 64];
    int bid = blockIdx.x;
    int qpart = bid & 3;
    int bc = bid >> 2;
    int ch = bc & 127;
    const float* qc = q + bc * NPIX + 784 * qpart;
    const float* kc = kbuf + bc * NPIX;
    const float* vc = vbuf + bc * NPIX;
    float* oc = out + bc * NPIX + 784 * qpart;
    float kbias = kb[ch], vbias = vb[ch];
    int qr0 = 14 * qpart;

    for (int i = threadIdx.x; i < 20 * 62; i += 256) {
        int yy = i / 62, xx = i - yy * 62;
        int gy = qr0 + yy - 3;
        int gx = xx - 3;
        bool in = (gy >= 0) && (gy < 56) && (gx >= 0) && (gx < 56);
        int off = in ? gy * 56 + gx : 0;
        float kv = in ? kc[off] : kbias;
        float vv = in ? vc[off] : vbias;
        sK[yy * SKS + xx] = kv;
        sV[yy * SKS + xx] = vv;
    }
    for (int i = threadIdx.x; i < SKS; i += 256) sV[20 * SKS + i] = 0.f;
    __syncthreads();

    int lane = threadIdx.x & 63;
    int wave = threadIdx.x >> 6;
    int k2 = min(lane, 48);
    int di = k2 / 7, dj = k2 - di * 7;
    float rbias = rb[di] + rb[7 + dj];
    int koff = di * SKS + dj;
    int t16 = lane & 15, p = lane >> 4;
    float* sWw = sW + wave * 64;

    // q software pipeline: prefetch group gl's q, then fetch gl+4 during gl
    int ulu = __builtin_amdgcn_readfirstlane(wave * 16);
    float4 p0 = *(const float4*)(qc + ulu);
    float4 p1 = *(const float4*)(qc + ulu + 4);
    float4 p2 = *(const float4*)(qc + ulu + 8);
    float4 p3 = *(const float4*)(qc + ulu + 12);

    for (int gl = wave; gl < 49; gl += 4) {
        int ul0 = gl * 16;
        int y0 = ul0 / 56;
        int x0 = ul0 - y0 * 56;

        float4 q0 = p0, q1 = p1, q2 = p2, q3 = p3;
        if (gl + 4 < 49) {
            int un = __builtin_amdgcn_readfirstlane((gl + 4) * 16);
            p0 = *(const float4*)(qc + un);
            p1 = *(const float4*)(qc + un + 4);
            p2 = *(const float4*)(qc + un + 8);
            p3 = *(const float4*)(qc + un + 12);
        }
        float qa[16] = {q0.x, q0.y, q0.z, q0.w, q1.x, q1.y, q1.z, q1.w,
                        q2.x, q2.y, q2.z, q2.w, q3.x, q3.y, q3.z, q3.w};
        float qs = 0.f;
        #pragma unroll
        for (int t = 0; t < 16; ++t) qs += qa[t];

        // --- qk: compile-time-offset LDS reads (merge into ds_read2) -----
        float acc = 0.f;
        const float* kb_ = sK + y0 * SKS + x0 + koff;
        if (x0 != 48) {
            #pragma unroll
            for (int t = 0; t < 16; ++t) acc += qa[t] * kb_[t];
        } else {
            const float* kb2 = sK + (y0 + 1) * SKS + koff;
            #pragma unroll
            for (int t = 0; t < 8; ++t) acc += qa[t] * kb_[t];
            #pragma unroll
            for (int t = 0; t < 8; ++t) acc += qa[8 + t] * kb2[t];
        }
        float val = (lane < 49) ? (acc + qs * rbias) : -1e30f;

        // --- softmax over 49 via DPP (VALU pipe) -------------------------
        float mS = wave_max(val);
        float e = __expf(val - mS);
        float sS = wave_sum(e);
        float wgt = e * __builtin_amdgcn_rcpf(sS);
        sWw[lane] = wgt;                       // lanes 49..63 write 0 pad

        // --- PV: lane = (t, ki-row-pair p); compile-time offsets ---------
        int u = ul0 + t16;
        int yt = u / 56;
        int xt = u - yt * 56;
        const float* vbase = sV + yt * SKS + xt + p * (2 * SKS);
        const float* wbase = sWw + p * 14;
        float oacc = 0.f;
        #pragma unroll
        for (int j = 0; j < 7; ++j) oacc += wbase[j] * vbase[j];
        #pragma unroll
        for (int j = 0; j < 7; ++j) oacc += wbase[7 + j] * vbase[SKS + j];
        oacc += __shfl_xor(oacc, 16);
        oacc += __shfl_xor(oacc, 32);
        if (lane < 16) oc[ul0 + lane] = oacc;
    }
}

extern "C" void kernel_launch(void* const* d_in, const int* in_sizes, int n_in,
                              void* d_out, int out_size, void* d_ws, size_t ws_size,
                              hipStream_t stream) {
    const float* x     = (const float*)d_in[0];
    const float* qw    = (const float*)d_in[1];
    const float* qb    = (const float*)d_in[2];
    const float* kw    = (const float*)d_in[3];
    const float* kb    = (const float*)d_in[4];
    const float* vw    = (const float*)d_in[5];
    const float* vb    = (const float*)d_in[6];
    const float* rel_h = (const float*)d_in[7];
    const float* rel_w = (const float*)d_in[8];
    float* out = (float*)d_out;

    float* ws   = (float*)d_ws;
    float* kbuf = ws;                    // 1605632
    float* vbuf = kbuf + 1605632;        // 1605632
    float* qbuf = vbuf + 1605632;        // 1605632
    float* w4q  = qbuf + 1605632;        // 16384
    float* w4k  = w4q + 16384;
    float* w4v  = w4k + 16384;
    float* rb   = w4v + 16384;           // 16

    prep_kernel<<<192, 256, 0, stream>>>(qw, kw, vw, rel_h, rel_w,
                                         w4q, w4k, w4v, rb);
    conv_kernel<<<784, 256, 0, stream>>>(x, w4q, w4k, w4v, qb, kb, vb,
                                         qbuf, kbuf, vbuf);
    attn_kernel<<<2048, 256, 0, stream>>>(qbuf, kbuf, vbuf, kb, vb, rb, out);
}